// Round 12
// baseline (353.269 us; speedup 1.0000x reference)
//
#include <hip/hip_runtime.h>
#include <hip/hip_fp16.h>

#define T_DIM 7
#define H_DIM 96
#define W_DIM 96
#define HW    (H_DIM*W_DIM)          // 9216
#define L_DIM (T_DIM*HW)             // 64512
#define NTAPS 27

#define SOFF_STRIDE 116              // bytes per loc row in offset LDS (29 dwords, coprime 32)
#define SMEM_B (16384 + 32*SOFF_STRIDE)

typedef __attribute__((ext_vector_type(8))) _Float16 f16x8;
typedef __attribute__((ext_vector_type(4))) float f32x4;

__device__ __forceinline__ void lds_barrier() {
    asm volatile("s_waitcnt lgkmcnt(0)" ::: "memory");
    __builtin_amdgcn_s_barrier();
    __builtin_amdgcn_sched_barrier(0);
}

#define GLOAD16(gp, lp) \
    __builtin_amdgcn_global_load_lds((const __attribute__((address_space(1))) unsigned int*)(gp), \
                                     (__attribute__((address_space(3))) unsigned int*)(lp), 16, 0, 0)

// ---------------------------------------------------------------------------
// prep_weights: [O][C][27] fp32 -> [27][O(64-pad)][C] f16, 16B slot rotated by o
// ---------------------------------------------------------------------------
__global__ void prep_weights(const float* __restrict__ woff0,
                             const float* __restrict__ w0,
                             const float* __restrict__ woff1,
                             const float* __restrict__ w1,
                             unsigned short* __restrict__ dst)
{
    int idx = blockIdx.x * 256 + threadIdx.x;
    const int per = NTAPS * 64 * 64;           // 110592
    if (idx >= 4 * per) return;
    int which = idx / per;
    int r     = idx % per;
    int tap   = r / 4096;
    int o     = (r >> 6) & 63;
    int c     = r & 63;
    const float* src = (which == 0) ? woff0 : (which == 1) ? w0
                     : (which == 2) ? woff1 : w1;
    int omax = (which == 0 || which == 2) ? 54 : 64;
    float v = 0.f;
    if (o < omax) v = src[(o * 64 + c) * NTAPS + tap];
    __half h = __float2half(v);
    int slot = (((c >> 3) + o) & 7);
    int pos  = tap * 4096 + o * 64 + slot * 8 + (c & 7);
    dst[which * per + pos] = __half_as_ushort(h);
}

// ---------------------------------------------------------------------------
// transpose_x: x [C=64][L] fp32 -> xt [L][64] f16 (linear, packed dwords)
// ---------------------------------------------------------------------------
__global__ void transpose_x(const float* __restrict__ x, unsigned* __restrict__ xt2)
{
    __shared__ float tile[64][65];
    const int tid = threadIdx.x;
    const int lb  = blockIdx.x * 64;
    const int ln  = tid & 63;
    const int q   = tid >> 6;    // 0..3
#pragma unroll
    for (int i = 0; i < 16; ++i) {
        int c = q + 4 * i;
        tile[ln][c] = x[(size_t)c * L_DIM + lb + ln];
    }
    __syncthreads();
    const int ln2 = tid & 31, q2 = tid >> 5;   // 0..7
#pragma unroll
    for (int i = 0; i < 8; ++i) {
        int ll = q2 + 8 * i;
        __half2 h2 = __float22half2_rn(make_float2(tile[ll][2*ln2], tile[ll][2*ln2+1]));
        xt2[(size_t)(lb + ll) * 32 + ln2] = *reinterpret_cast<unsigned*>(&h2);
    }
}

// ---- per-tap helpers: K-split (each wave gathers its 32-channel half) ------
#define PARAMS_ISSUE(K, O2) { \
    int kt_ = (K) / 9; int r9_ = (K) - kt_ * 9; \
    int kh_ = r9_ / 3; int kw_ = r9_ - kh_ * 3; \
    int tp_ = t + kt_ - 1; \
    bool tv_ = (tp_ >= 0) && (tp_ < T_DIM); \
    int tb_ = (tv_ ? tp_ : 0) * HW; \
    if (DEFORM) { \
        float ph_ = (float)(h + kh_ - 1) + (O2).x; \
        float pw_ = (float)(w + kw_ - 1) + (O2).y; \
        float h0f_ = floorf(ph_), w0f_ = floorf(pw_); \
        float lh_ = ph_ - h0f_, lw_ = pw_ - w0f_; \
        int h0_ = (int)h0f_, w0_ = (int)w0f_; \
        _Pragma("unroll") \
        for (int j = 0; j < 4; ++j) { \
            int hj_ = h0_ + (j >> 1), wj_ = w0_ + (j & 1); \
            bool v_ = tv_ && (hj_ >= 0) && (hj_ < H_DIM) && (wj_ >= 0) && (wj_ < W_DIM); \
            float wh_  = (j >> 1) ? lh_ : 1.f - lh_; \
            float wwt_ = (j & 1)  ? lw_ : 1.f - lw_; \
            int hc_ = min(max(hj_, 0), H_DIM - 1); \
            int wc_ = min(max(wj_, 0), W_DIM - 1); \
            cwh[j] = __float2half2_rn(v_ ? wh_ * wwt_ : 0.f); \
            int cb_ = (tb_ + hc_ * W_DIM + wc_) * 128 + choff; \
            g[j] = *(const int4*)(xb + cb_); \
        } \
    } else { \
        int hj_ = h + kh_ - 1, wj_ = w + kw_ - 1; \
        bool v_ = tv_ && (hj_ >= 0) && (hj_ < H_DIM) && (wj_ >= 0) && (wj_ < W_DIM); \
        int hc_ = min(max(hj_, 0), H_DIM - 1); \
        int wc_ = min(max(wj_, 0), W_DIM - 1); \
        cw0 = v_ ? 1.f : 0.f; \
        int cb_ = (tb_ + hc_ * W_DIM + wc_) * 128 + choff; \
        g[0] = *(const int4*)(xb + cb_); \
    } }

#define CONSUME(A0) { \
    if (DEFORM) { \
        __align__(16) __half2 va_[4]; \
        const __half2 z2_ = __float2half2_rn(0.f); \
        _Pragma("unroll") \
        for (int p = 0; p < 4; ++p) va_[p] = z2_; \
        _Pragma("unroll") \
        for (int j = 0; j < 4; ++j) { \
            const __half2* p0_ = (const __half2*)&g[j]; \
            _Pragma("unroll") \
            for (int d = 0; d < 4; ++d) \
                va_[d] = __hfma2(p0_[d], cwh[j], va_[d]); \
        } \
        A0 = *reinterpret_cast<f16x8*>(&va_[0]); \
    } else { \
        int4 z0_ = g[0]; \
        if (cw0 == 0.f) z0_ = make_int4(0,0,0,0); \
        A0 = *reinterpret_cast<f16x8*>(&z0_); \
    } }

// ---------------------------------------------------------------------------
// dcn_fused: one kernel per layer, 256 threads, 32 locs/block, grid 2016
// (8 blocks/CU -> 32 waves/CU at VGPR<=64). 4 waves = 2 loc-groups x 2 K-halves.
//   Phase A: offset conv -> offsets (f16) in LDS (K-split + reduce)
//   Phase B: deformable conv (K-split + reduce)
//   EPI 1: +bias+leaky -> f16 [loc][64].  EPI 2: +bias+residual -> f32 NCDHW.
// ---------------------------------------------------------------------------
template<int EPI>
__global__ __launch_bounds__(256, 8)
void dcn_fused(const unsigned short* __restrict__ xin,   // f16 [L][64]
               const unsigned short* __restrict__ Wtoff, // f16 [27][64][64] swz
               const unsigned short* __restrict__ Wtm,   // f16 [27][64][64] swz
               const float* __restrict__ boff,           // [54]
               const float* __restrict__ bmain,          // [64]
               const float* __restrict__ resid,          // f32 NCDHW (EPI==2)
               float* __restrict__ outf,
               unsigned short* __restrict__ outh)
{
    __shared__ __align__(16) unsigned char smem[SMEM_B];
    unsigned char* wbuf = smem;            // 2 x 8KB weight double-buffer (reused as reduce/tf)
    unsigned char* soff = smem + 16384;    // offsets: 32 locs x SOFF_STRIDE

    const int tid  = threadIdx.x;
    const int wv   = tid >> 6, lane = tid & 63;
    const int lr   = lane & 15, lk = lane >> 4;
    const int gidx = wv >> 1;              // loc group (0,1)
    const int half = wv & 1;               // K half (0,1)
    const int choff = half * 64 + lk * 16; // byte offset into 128B channel row

    // XCD-contiguous swizzle: 2016 = 8 x 252 (bijective)
    const int bid = blockIdx.x;
    const int wg  = (bid & 7) * 252 + (bid >> 3);
    const int t    = wg / 288;
    const int tile = wg - t * 288;
    const int lbase = t * HW + tile * 32 + gidx * 16;

    const int mypos = tile * 32 + gidx * 16 + lr;
    const int h = mypos / W_DIM;
    const int w = mypos - h * W_DIM;

    const unsigned char* xb = (const unsigned char*)xin;

    // weight B-read slot offset (2-way, free): row o=n*16+lr, chunk cc=half*4+lk
    const int sb = ((half * 4 + lk + lr) & 7) << 4;

    int4    g[4];
    __half2 cwh[4];
    float   cw0 = 0.f;

    f32x4 acc[4];

    // ===================== PHASE A: offset conv (K-split) =====================
    {
        constexpr bool DEFORM = false;
        const unsigned char* wgbl = (const unsigned char*)Wtoff;
#pragma unroll
        for (int n = 0; n < 4; ++n) acc[n] = (f32x4){0.f, 0.f, 0.f, 0.f};

        GLOAD16(wgbl + tid * 16,        wbuf + wv * 1024);
        GLOAD16(wgbl + 4096 + tid * 16, wbuf + 4096 + wv * 1024);
        float2 o2z = make_float2(0.f, 0.f);
        PARAMS_ISSUE(0, o2z);

#pragma unroll 1
        for (int k = 0; k < NTAPS; ++k) {
            asm volatile("s_waitcnt vmcnt(1)" ::: "memory");   // drain W(k), keep gather(k)
            lds_barrier();
            if (k + 1 < NTAPS) {
                const unsigned char* wsrc = wgbl + (size_t)(k + 1) * 8192 + tid * 16;
                unsigned char* ld = wbuf + (((k + 1) & 1) << 13) + wv * 1024;
                GLOAD16(wsrc,        ld);
                GLOAD16(wsrc + 4096, ld + 4096);
            }
            f16x8 a0;
            CONSUME(a0);
            if (k + 1 < NTAPS) { PARAMS_ISSUE(k + 1, o2z); }
            const unsigned char* br = wbuf + ((k & 1) << 13) + lr * 128;
#pragma unroll
            for (int n = 0; n < 4; ++n) {
                f16x8 b0 = *(const f16x8*)(br + n * 2048 + sb);
                acc[n] = __builtin_amdgcn_mfma_f32_16x16x32_f16(a0, b0, acc[n], 0, 0, 0);
            }
        }

        // ---- reduce across K-halves, then write offsets (f16) to LDS
        __syncthreads();
        if (half == 1) {
#pragma unroll
            for (int n = 0; n < 4; ++n)
                *(f32x4*)(wbuf + gidx * 4096 + n * 1024 + lane * 16) = acc[n];
        }
        __syncthreads();
        if (half == 0) {
#pragma unroll
            for (int n = 0; n < 4; ++n) {
                f32x4 other = *(const f32x4*)(wbuf + gidx * 4096 + n * 1024 + lane * 16);
                int o = n * 16 + lr;
                float bvA = (o < 54) ? boff[o] : 0.f;
#pragma unroll
                for (int i = 0; i < 4; ++i) {
                    if (o < 54) {
                        int row = gidx * 16 + lk * 4 + i;
                        float vv = acc[n][i] + other[i] + bvA;
                        *(unsigned short*)(soff + row * SOFF_STRIDE + o * 2) =
                            __half_as_ushort(__float2half(vv));
                    }
                }
            }
        }
    }
    __syncthreads();   // offsets ready; wbuf free for phase B

    // ===================== PHASE B: deformable conv (K-split) =====================
    {
        constexpr bool DEFORM = true;
        const unsigned char* wgbl = (const unsigned char*)Wtm;
        const unsigned char* myoff = soff + (gidx * 16 + lr) * SOFF_STRIDE;
#pragma unroll
        for (int n = 0; n < 4; ++n) acc[n] = (f32x4){0.f, 0.f, 0.f, 0.f};

        GLOAD16(wgbl + tid * 16,        wbuf + wv * 1024);
        GLOAD16(wgbl + 4096 + tid * 16, wbuf + 4096 + wv * 1024);
        unsigned u0 = *(const unsigned*)(myoff);
        float2 o2a = __half22float2(*reinterpret_cast<__half2*>(&u0));
        unsigned u1 = *(const unsigned*)(myoff + 4);
        float2 o2n = __half22float2(*reinterpret_cast<__half2*>(&u1));
        PARAMS_ISSUE(0, o2a);

#pragma unroll 1
        for (int k = 0; k < NTAPS; ++k) {
            asm volatile("s_waitcnt vmcnt(4)" ::: "memory");   // drain W(k), keep gathers(k)
            lds_barrier();
            if (k + 1 < NTAPS) {
                const unsigned char* wsrc = wgbl + (size_t)(k + 1) * 8192 + tid * 16;
                unsigned char* ld = wbuf + (((k + 1) & 1) << 13) + wv * 1024;
                GLOAD16(wsrc,        ld);
                GLOAD16(wsrc + 4096, ld + 4096);
            }
            float2 onext = make_float2(0.f, 0.f);
            if (k + 2 < NTAPS) {
                unsigned un = *(const unsigned*)(myoff + 4 * (k + 2));
                onext = __half22float2(*reinterpret_cast<__half2*>(&un));
            }
            f16x8 a0;
            CONSUME(a0);
            if (k + 1 < NTAPS) { PARAMS_ISSUE(k + 1, o2n); }
            o2n = onext;
            const unsigned char* br = wbuf + ((k & 1) << 13) + lr * 128;
#pragma unroll
            for (int n = 0; n < 4; ++n) {
                f16x8 b0 = *(const f16x8*)(br + n * 2048 + sb);
                acc[n] = __builtin_amdgcn_mfma_f32_16x16x32_f16(a0, b0, acc[n], 0, 0, 0);
            }
        }

        // ---- reduce across K-halves
        __syncthreads();
        if (half == 1) {
#pragma unroll
            for (int n = 0; n < 4; ++n)
                *(f32x4*)(wbuf + gidx * 4096 + n * 1024 + lane * 16) = acc[n];
        }
        __syncthreads();
        if (half == 1) return;

#pragma unroll
        for (int n = 0; n < 4; ++n) {
            f32x4 other = *(const f32x4*)(wbuf + gidx * 4096 + n * 1024 + lane * 16);
            acc[n][0] += other[0]; acc[n][1] += other[1];
            acc[n][2] += other[2]; acc[n][3] += other[3];
        }

        // ---- epilogue (half==0 waves). C/D: col = lr, row = lk*4+i
        float bv[4];
#pragma unroll
        for (int n = 0; n < 4; ++n) bv[n] = bmain[n * 16 + lr];

        if (EPI == 1) {
#pragma unroll
            for (int n = 0; n < 4; ++n)
#pragma unroll
                for (int i = 0; i < 4; ++i) {
                    int row = lk * 4 + i;
                    float vv = acc[n][i] + bv[n];
                    vv = (vv > 0.f) ? vv : 0.1f * vv;
                    outh[(size_t)(lbase + row) * 64 + n * 16 + lr] =
                        __half_as_ushort(__float2half(vv));
                }
        } else {
            // transpose via own group's 4KB region (WAR within this wave only)
            float* tf = (float*)(wbuf + gidx * 4096);
#pragma unroll
            for (int n = 0; n < 4; ++n)
#pragma unroll
                for (int i = 0; i < 4; ++i) {
                    int row = lk * 4 + i;
                    int och = n * 16 + lr;
                    tf[row * 64 + ((och + 2 * row) & 63)] = acc[n][i] + bv[n];
                }
            asm volatile("s_waitcnt lgkmcnt(0)" ::: "memory");
            __builtin_amdgcn_sched_barrier(0);
            int j = lane & 15, gq = lane >> 4;
#pragma unroll
            for (int it = 0; it < 16; ++it) {
                int och = gq * 16 + it;
                float val = tf[j * 64 + ((och + 2 * j) & 63)];
                size_t gi = (size_t)och * L_DIM + lbase + j;
                outf[gi] = val + resid[gi];
            }
        }
    }
}

// ---------------------------------------------------------------------------
extern "C" void kernel_launch(void* const* d_in, const int* in_sizes, int n_in,
                              void* d_out, int out_size, void* d_ws, size_t ws_size,
                              hipStream_t stream)
{
    const float* x     = (const float*)d_in[0];
    const float* woff0 = (const float*)d_in[1];
    const float* boff0 = (const float*)d_in[2];
    const float* w0    = (const float*)d_in[3];
    const float* b0    = (const float*)d_in[4];
    const float* woff1 = (const float*)d_in[5];
    const float* boff1 = (const float*)d_in[6];
    const float* w1    = (const float*)d_in[7];
    const float* b1    = (const float*)d_in[8];
    float* out = (float*)d_out;

    unsigned char* ws = (unsigned char*)d_ws;
    unsigned short* Wt  = (unsigned short*)ws;                  // 884736 B (4x f16 [27][64][64] swz)
    unsigned short* xt  = (unsigned short*)(ws + 884736);       // 8257536 B f16 [L][64]
    unsigned short* y   = (unsigned short*)(ws + 9142272);      // 8257536 B f16 [L][64]

    prep_weights<<<1728, 256, 0, stream>>>(woff0, w0, woff1, w1, Wt);
    transpose_x<<<1008, 256, 0, stream>>>(x, (unsigned*)xt);

    const int grid = L_DIM / 32;          // 2016 blocks x 256 threads
    const int WSZ  = NTAPS * 64 * 64;     // 110592

    // layer 0 (fused offset-conv + deform + leaky) : xt -> y
    dcn_fused<1><<<grid, 256, 0, stream>>>(xt, Wt,           Wt + WSZ,     boff0, b0, nullptr, nullptr, y);
    // layer 1 (fused offset-conv + deform + residual) : y -> out
    dcn_fused<2><<<grid, 256, 0, stream>>>(y,  Wt + 2 * WSZ, Wt + 3 * WSZ, boff1, b1, x, out, nullptr);
}

// Round 13
// 129.244 us; speedup vs baseline: 2.7333x; 2.7333x over previous
//
#include <hip/hip_runtime.h>
#include <hip/hip_fp16.h>

#define T_DIM 7
#define H_DIM 96
#define W_DIM 96
#define HW    (H_DIM*W_DIM)          // 9216
#define L_DIM (T_DIM*HW)             // 64512
#define NTAPS 27

// tile geometry: 8 rows x 16 cols = 128 locs per block, wave = one image row
#define TR 8
#define TC 16
#define HR (TR+8)                    // 16 halo rows
#define HC (TC+8)                    // 24 halo cols
#define HROWB (HC*128)               // 3072 B per halo row
#define HALO_B (HR*HROWB)            // 49152
#define WBUF_OFF HALO_B              // 49152 (2 x 8KB weight dbuf)
#define SOFF_OFF (HALO_B + 16384)    // 65536
#define SOFF_STRIDE 116              // 29 dwords per loc (bank-spread)
#define SMEM_B (SOFF_OFF + 128*SOFF_STRIDE)   // 80384 <= 81920 (2 blocks/CU)

typedef __attribute__((ext_vector_type(8))) _Float16 f16x8;
typedef __attribute__((ext_vector_type(4))) float f32x4;

#define GLOAD16(gp, lp) \
    __builtin_amdgcn_global_load_lds((const __attribute__((address_space(1))) unsigned int*)(gp), \
                                     (__attribute__((address_space(3))) unsigned int*)(lp), 16, 0, 0)

// ---------------------------------------------------------------------------
// prep_weights: [O][C][27] fp32 -> [27][O(64-pad)][C] f16, 16B slot rotated by o
// ---------------------------------------------------------------------------
__global__ void prep_weights(const float* __restrict__ woff0,
                             const float* __restrict__ w0,
                             const float* __restrict__ woff1,
                             const float* __restrict__ w1,
                             unsigned short* __restrict__ dst)
{
    int idx = blockIdx.x * 256 + threadIdx.x;
    const int per = NTAPS * 64 * 64;           // 110592
    if (idx >= 4 * per) return;
    int which = idx / per;
    int r     = idx % per;
    int tap   = r / 4096;
    int o     = (r >> 6) & 63;
    int c     = r & 63;
    const float* src = (which == 0) ? woff0 : (which == 1) ? w0
                     : (which == 2) ? woff1 : w1;
    int omax = (which == 0 || which == 2) ? 54 : 64;
    float v = 0.f;
    if (o < omax) v = src[(o * 64 + c) * NTAPS + tap];
    __half h = __float2half(v);
    int slot = (((c >> 3) + o) & 7);
    int pos  = tap * 4096 + o * 64 + slot * 8 + (c & 7);
    dst[which * per + pos] = __half_as_ushort(h);
}

// ---------------------------------------------------------------------------
// transpose_x: x [C=64][L] fp32 -> xt [L][64] f16 (linear, packed dwords)
// ---------------------------------------------------------------------------
__global__ void transpose_x(const float* __restrict__ x, unsigned* __restrict__ xt2)
{
    __shared__ float tile[64][65];
    const int tid = threadIdx.x;
    const int lb  = blockIdx.x * 64;
    const int ln  = tid & 63;
    const int q   = tid >> 6;    // 0..3
#pragma unroll
    for (int i = 0; i < 16; ++i) {
        int c = q + 4 * i;
        tile[ln][c] = x[(size_t)c * L_DIM + lb + ln];
    }
    __syncthreads();
    const int ln2 = tid & 31, q2 = tid >> 5;   // 0..7
#pragma unroll
    for (int i = 0; i < 8; ++i) {
        int ll = q2 + 8 * i;
        __half2 h2 = __float22half2_rn(make_float2(tile[ll][2*ln2], tile[ll][2*ln2+1]));
        xt2[(size_t)(lb + ll) * 32 + ln2] = *reinterpret_cast<unsigned*>(&h2);
    }
}

// ---- stage halo slab for kt (48KB) with SOURCE-pre-swizzled gload_lds ------
// LDS pos (hr,hc,slot) holds chunk (slot-hc)&7 of cell (hr,hc) -> readers use
// slot=(chunk+hc)&7 (col-keyed, 2-way-free for row-of-locs waves).
#define STAGE_SLAB(KT) { \
    int tp_ = t + (KT) - 1; \
    int tps_ = min(max(tp_, 0), T_DIM - 1); \
    const unsigned char* sb_ = xb + (size_t)tps_ * HW * 128; \
    _Pragma("unroll") \
    for (int i = 0; i < 6; ++i) { \
        int p16_ = tid + i * 512; \
        int hr_ = p16_ / 192; \
        int rem_ = p16_ - hr_ * 192; \
        int hc_ = rem_ >> 3; \
        int sl_ = rem_ & 7; \
        int ch_ = (sl_ - hc_) & 7; \
        int gr_ = min(max(row0 - 4 + hr_, 0), H_DIM - 1); \
        int gc_ = min(max(col0 - 4 + hc_, 0), W_DIM - 1); \
        GLOAD16(sb_ + (size_t)(gr_ * W_DIM + gc_) * 128 + ch_ * 16, \
                smem + (i << 13) + (wv << 10)); \
    } }

#define WSTAGE(WGBL, K) \
    GLOAD16((WGBL) + (size_t)(K) * 8192 + tid * 16, \
            smem + WBUF_OFF + (((K) & 1) << 13) + (wv << 10));

// ---- one conv phase (27 taps) reading A from halo LDS ----------------------
#define RUN_PHASE(DEF, WGBL) { \
    STAGE_SLAB(0); \
    WSTAGE(WGBL, 0); \
    asm volatile("s_waitcnt vmcnt(0)" ::: "memory"); \
    __builtin_amdgcn_s_barrier(); \
    __builtin_amdgcn_sched_barrier(0); \
    const unsigned char* soffp_ = smem + SOFF_OFF + (wv * 16 + lr) * SOFF_STRIDE; \
    float2 o2n_ = make_float2(0.f, 0.f); \
    if (DEF) { unsigned u_ = *(const unsigned*)(soffp_); \
               o2n_ = __half22float2(*reinterpret_cast<__half2*>(&u_)); } \
    _Pragma("unroll 1") \
    for (int kt = 0; kt < 3; ++kt) { \
        if (kt > 0) { \
            asm volatile("s_waitcnt lgkmcnt(0)" ::: "memory"); \
            __builtin_amdgcn_s_barrier();            /* all done reading slab kt-1 */ \
            STAGE_SLAB(kt); \
            asm volatile("s_waitcnt vmcnt(0)" ::: "memory"); \
            __builtin_amdgcn_s_barrier(); \
            __builtin_amdgcn_sched_barrier(0); \
        } \
        int tp = t + kt - 1; \
        bool tv = (tp >= 0) && (tp < T_DIM); \
        _Pragma("unroll 1") \
        for (int k9 = 0; k9 < 9; ++k9) { \
            int k = kt * 9 + k9; \
            if (k > 0) { \
                asm volatile("s_waitcnt vmcnt(0) lgkmcnt(0)" ::: "memory"); /* W(k) landed; prev buf readers done */ \
                __builtin_amdgcn_s_barrier(); \
                __builtin_amdgcn_sched_barrier(0); \
            } \
            if (k + 1 < NTAPS) { WSTAGE(WGBL, k + 1); } \
            int kh = k9 / 3, kw = k9 - (k9 / 3) * 3; \
            f16x8 a0, a1; \
            if (DEF) { \
                float2 o2_ = o2n_; \
                if (k + 1 < NTAPS) { \
                    unsigned un_ = *(const unsigned*)(soffp_ + 4 * (k + 1)); \
                    o2n_ = __half22float2(*reinterpret_cast<__half2*>(&un_)); \
                } \
                float ph_ = (float)(row0 + wv + kh - 1) + o2_.x; \
                float pw_ = (float)(col0 + lr + kw - 1) + o2_.y; \
                float hf_ = floorf(ph_), wf_ = floorf(pw_); \
                float lh_ = ph_ - hf_, lw_ = pw_ - wf_; \
                int h0_ = (int)hf_, w0_ = (int)wf_; \
                __align__(16) __half2 va_[8]; \
                const __half2 z2_ = __float2half2_rn(0.f); \
                _Pragma("unroll") \
                for (int p = 0; p < 8; ++p) va_[p] = z2_; \
                _Pragma("unroll") \
                for (int j = 0; j < 4; ++j) { \
                    int hj_ = h0_ + (j >> 1), wj_ = w0_ + (j & 1); \
                    bool val_ = tv && (hj_ >= 0) && (hj_ < H_DIM) && (wj_ >= 0) && (wj_ < W_DIM); \
                    float wgt_ = ((j >> 1) ? lh_ : 1.f - lh_) * ((j & 1) ? lw_ : 1.f - lw_); \
                    __half2 cw_ = __float2half2_rn(val_ ? wgt_ : 0.f); \
                    int sr_ = min(max(hj_ - row0 + 4, 0), HR - 1); \
                    int sc_ = min(max(wj_ - col0 + 4, 0), HC - 1); \
                    const unsigned char* cell_ = smem + sr_ * HROWB + sc_ * 128; \
                    f16x8 c0_ = *(const f16x8*)(cell_ + (((lk + sc_) & 7) << 4)); \
                    f16x8 c1_ = *(const f16x8*)(cell_ + (((lk + 4 + sc_) & 7) << 4)); \
                    const __half2* p0_ = (const __half2*)&c0_; \
                    const __half2* p1_ = (const __half2*)&c1_; \
                    _Pragma("unroll") \
                    for (int d = 0; d < 4; ++d) { \
                        va_[d]     = __hfma2(p0_[d], cw_, va_[d]); \
                        va_[4 + d] = __hfma2(p1_[d], cw_, va_[4 + d]); \
                    } \
                } \
                a0 = *reinterpret_cast<f16x8*>(&va_[0]); \
                a1 = *reinterpret_cast<f16x8*>(&va_[4]); \
            } else { \
                int hj_ = row0 + wv + kh - 1, wj_ = col0 + lr + kw - 1; \
                bool val_ = tv && (hj_ >= 0) && (hj_ < H_DIM) && (wj_ >= 0) && (wj_ < W_DIM); \
                int sr_ = wv + kh + 3, sc_ = lr + kw + 3; \
                const unsigned char* cell_ = smem + sr_ * HROWB + sc_ * 128; \
                int4 z0_ = *(const int4*)(cell_ + (((lk + sc_) & 7) << 4)); \
                int4 z1_ = *(const int4*)(cell_ + (((lk + 4 + sc_) & 7) << 4)); \
                if (!val_) { z0_ = make_int4(0,0,0,0); z1_ = make_int4(0,0,0,0); } \
                a0 = *reinterpret_cast<f16x8*>(&z0_); \
                a1 = *reinterpret_cast<f16x8*>(&z1_); \
            } \
            const unsigned char* br_ = smem + WBUF_OFF + ((k & 1) << 13) + lr * 128; \
            _Pragma("unroll") \
            for (int n = 0; n < 4; ++n) { \
                f16x8 b0_ = *(const f16x8*)(br_ + n * 2048 + s0); \
                f16x8 b1_ = *(const f16x8*)(br_ + n * 2048 + s1); \
                acc[n] = __builtin_amdgcn_mfma_f32_16x16x32_f16(a0, b0_, acc[n], 0, 0, 0); \
                acc[n] = __builtin_amdgcn_mfma_f32_16x16x32_f16(a1, b1_, acc[n], 0, 0, 0); \
            } \
        } \
    } }

// ---------------------------------------------------------------------------
// dcn_tile: fused (offset conv + deformable conv), halo-LDS gathers.
//   EPI 1: +bias+leaky -> f16 [loc][64].  EPI 2: +bias+residual -> f32 NCDHW.
// ---------------------------------------------------------------------------
template<int EPI>
__global__ __launch_bounds__(512, 2)
void dcn_tile(const unsigned short* __restrict__ xin,   // f16 [L][64]
              const unsigned short* __restrict__ Wtoff, // f16 [27][64][64] swz
              const unsigned short* __restrict__ Wtm,   // f16 [27][64][64] swz
              const float* __restrict__ boff,           // [54]
              const float* __restrict__ bmain,          // [64]
              const float* __restrict__ resid,          // f32 NCDHW (EPI==2)
              float* __restrict__ outf,
              unsigned short* __restrict__ outh)
{
    __shared__ __align__(16) unsigned char smem[SMEM_B];

    const int tid  = threadIdx.x;
    const int wv   = tid >> 6, lane = tid & 63;
    const int lr   = lane & 15, lk = lane >> 4;

    // XCD-contiguous swizzle: 504 = 8 x 63 (bijective)
    const int bid = blockIdx.x;
    const int wg  = (bid & 7) * 63 + (bid >> 3);
    const int t   = wg / 72;
    const int rg  = (wg % 72) / 6;
    const int cg  = wg % 6;
    const int row0 = rg * TR;
    const int col0 = cg * TC;
    const int lrow = t * HW + (row0 + wv) * W_DIM + col0;   // wave's first loc

    const unsigned char* xb = (const unsigned char*)xin;

    // weight B-read slot offsets (2-way, free)
    const int s0 = ((lk + lr) & 7) << 4;
    const int s1 = ((lk + 4 + lr) & 7) << 4;

    f32x4 acc[4];
#pragma unroll
    for (int n = 0; n < 4; ++n) acc[n] = (f32x4){0.f, 0.f, 0.f, 0.f};

    // ================ PHASE A: offset conv -> soff LDS ================
    RUN_PHASE(false, (const unsigned char*)Wtoff);

#pragma unroll
    for (int n = 0; n < 4; ++n) {
        int o = n * 16 + lr;
        if (o < 54) {
            float bvA = boff[o];
#pragma unroll
            for (int i = 0; i < 4; ++i) {
                int loc = wv * 16 + lk * 4 + i;       // block-local loc (row wv, col lk*4+i)
                float vv = acc[n][i] + bvA;
                *(unsigned short*)(smem + SOFF_OFF + loc * SOFF_STRIDE + o * 2) =
                    __half_as_ushort(__float2half(vv));
            }
        }
    }
    __syncthreads();

    // ================ PHASE B: deformable conv ================
#pragma unroll
    for (int n = 0; n < 4; ++n) acc[n] = (f32x4){0.f, 0.f, 0.f, 0.f};

    RUN_PHASE(true, (const unsigned char*)Wtm);

    // ---- epilogue. C/D: col=lr (out ch within n*16), row=lk*4+i (loc col)
    float bv[4];
#pragma unroll
    for (int n = 0; n < 4; ++n) bv[n] = bmain[n * 16 + lr];

    if (EPI == 1) {
#pragma unroll
        for (int n = 0; n < 4; ++n)
#pragma unroll
            for (int i = 0; i < 4; ++i) {
                int lc = lk * 4 + i;
                float vv = acc[n][i] + bv[n];
                vv = (vv > 0.f) ? vv : 0.1f * vv;
                outh[(size_t)(lrow + lc) * 64 + n * 16 + lr] =
                    __half_as_ushort(__float2half(vv));
            }
    } else {
        __syncthreads();   // halo dead; per-wave 4KB transpose regions
        float* tf = (float*)(smem + (wv << 12));
#pragma unroll
        for (int n = 0; n < 4; ++n)
#pragma unroll
            for (int i = 0; i < 4; ++i) {
                int lc = lk * 4 + i;
                int och = n * 16 + lr;
                tf[lc * 64 + ((och + 2 * lc) & 63)] = acc[n][i] + bv[n];
            }
        asm volatile("s_waitcnt lgkmcnt(0)" ::: "memory");
        __builtin_amdgcn_sched_barrier(0);
        int j = lane & 15, gq = lane >> 4;
#pragma unroll
        for (int it = 0; it < 16; ++it) {
            int och = gq * 16 + it;
            float val = tf[j * 64 + ((och + 2 * j) & 63)];
            size_t gi = (size_t)och * L_DIM + lrow + j;
            outf[gi] = val + resid[gi];
        }
    }
}

// ---------------------------------------------------------------------------
extern "C" void kernel_launch(void* const* d_in, const int* in_sizes, int n_in,
                              void* d_out, int out_size, void* d_ws, size_t ws_size,
                              hipStream_t stream)
{
    const float* x     = (const float*)d_in[0];
    const float* woff0 = (const float*)d_in[1];
    const float* boff0 = (const float*)d_in[2];
    const float* w0    = (const float*)d_in[3];
    const float* b0    = (const float*)d_in[4];
    const float* woff1 = (const float*)d_in[5];
    const float* boff1 = (const float*)d_in[6];
    const float* w1    = (const float*)d_in[7];
    const float* b1    = (const float*)d_in[8];
    float* out = (float*)d_out;

    unsigned char* ws = (unsigned char*)d_ws;
    unsigned short* Wt  = (unsigned short*)ws;                  // 884736 B (4x f16 [27][64][64] swz)
    unsigned short* xt  = (unsigned short*)(ws + 884736);       // 8257536 B f16 [L][64]
    unsigned short* y   = (unsigned short*)(ws + 9142272);      // 8257536 B f16 [L][64]

    prep_weights<<<1728, 256, 0, stream>>>(woff0, w0, woff1, w1, Wt);
    transpose_x<<<1008, 256, 0, stream>>>(x, (unsigned*)xt);

    const int grid = T_DIM * (H_DIM / TR) * (W_DIM / TC);   // 7*12*6 = 504
    const int WSZ  = NTAPS * 64 * 64;                       // 110592

    // layer 0 (fused offset-conv + deform + leaky) : xt -> y
    dcn_tile<1><<<grid, 512, 0, stream>>>(xt, Wt,           Wt + WSZ,     boff0, b0, nullptr, nullptr, y);
    // layer 1 (fused offset-conv + deform + residual) : y -> out
    dcn_tile<2><<<grid, 512, 0, stream>>>(y,  Wt + 2 * WSZ, Wt + 3 * WSZ, boff1, b1, x, out, nullptr);
}